// Round 11
// baseline (220.333 us; speedup 1.0000x reference)
//
#include <hip/hip_runtime.h>
#include <hip/hip_fp16.h>
#include <math.h>

#define FDIM  128
#define L1OUT 16
#define L2DIM 17
#define TRM   64      // f-rows per block (R6-proven geometry)
#define HSTR  136     // LDS tile row stride in halves (272 B: 2-way-only conflicts)

typedef _Float16 f16x8 __attribute__((ext_vector_type(8)));   // MFMA A/B frag (4 VGPR)
typedef float    f32x4 __attribute__((ext_vector_type(4)));   // MFMA C/D frag
typedef int      ix4  __attribute__((ext_vector_type(4)));    // nt-load vehicles
typedef float    fx4  __attribute__((ext_vector_type(4)));

// one 32-byte fp16 node row (16 halves); align 16 -> 2x global_load_dwordx4
struct __align__(16) H16 { __half2 h[8]; };

__device__ __forceinline__ float lrelu(float v) { return v >= 0.f ? v : 0.1f * v; }

// ============================================================================
// R11 EXPERIMENT (single mechanism): cross-XCD dirty-line theory. K1's A/B
// stores (and deg atomics) leave lines DIRTY in one XCD's L2; K2's random
// gathers from other XCDs hit remote-dirty lines (~900cy writeback/forward
// path vs ~200 clean-L2 / ~450 L3). Evidence: R9 -- byte-identical edge_mlp
// swung 58->81 when only the A/B WRITER geometry changed, with FETCH *lower*.
// Model: 15.6k gathers/CU x 900cy / ~96 outstanding = 70us (matches 58-81
// observed); clean-L3 serves the same at ~23us. Fix: non-temporal stores for
// A/B (never dirty in a private L2) + nt loads/stores for ALL read-once/
// write-once streams (f, ind, val, eout, out) so they stop evicting the
// gather working set. A/B GATHER loads stay cached (that's what L2 is for).
// R10 lesson: tail-atomics placement != temporal separation (early blocks'
// tails overlap late blocks' loads); kept tail form anyway (marginally
// better, 59.6->56) since the split costs a ~25us dispatch boundary.
// R4 lesson (permanent): cooperative grid.sync fusion -> 176us. Deleted.
// ============================================================================
__global__ void node_transform(
    const float* __restrict__ f, const float* __restrict__ W1,
    const float* __restrict__ b1,
    const int* __restrict__ ind_i, const float* __restrict__ val,
    H16* __restrict__ A, H16* __restrict__ B,
    float* __restrict__ deg, int N, int E)
{
    __shared__ __align__(16) _Float16 tile[TRM * HSTR];   // 17.4 KB

    const int t    = threadIdx.x;
    const int lane = t & 63;
    const int wv   = t >> 6;          // wave 0..3 -> M-subtile wv
    const int n    = lane & 15;       // MFMA matrix-dim index (col)
    const int quad = lane >> 4;       // k-block / row-group selector

    // ---- load W' B-frags once per block: bfr[nt][ks], k = 32*ks + 8*quad + j
    f16x8 bfr[2][4];
#pragma unroll
    for (int nt = 0; nt < 2; ++nt)
#pragma unroll
        for (int ks = 0; ks < 4; ++ks) {
            f16x8 bf;
#pragma unroll
            for (int j = 0; j < 8; ++j) {
                int k = 32 * ks + 8 * quad + j;
                bf[j] = (_Float16)W1[(size_t)(nt * FDIM + k) * L1OUT + n];
            }
            bfr[nt][ks] = bf;
        }
    float b1v = b1[n];                // folded into nt=0 accumulator init

    // ---- stage 64 f-rows as fp16 into padded LDS tile (nt: read-once) ----
    const int base = blockIdx.x * TRM;
#pragma unroll
    for (int q = 0; q < 4; ++q) {
        int p  = t + 256 * q;         // half8-chunk index 0..1023
        int r  = p >> 4;              // 16 chunks per row
        int c8 = p & 15;              // chunk within row (8 halves)
        fx4 lo = {0.f, 0.f, 0.f, 0.f};
        fx4 hi = lo;
        if (base + r < N) {
            const fx4* src = reinterpret_cast<const fx4*>(
                f + (size_t)(base + r) * FDIM + c8 * 8);
            lo = __builtin_nontemporal_load(src);
            hi = __builtin_nontemporal_load(src + 1);
        }
        f16x8 hx;
        hx[0] = (_Float16)lo[0]; hx[1] = (_Float16)lo[1];
        hx[2] = (_Float16)lo[2]; hx[3] = (_Float16)lo[3];
        hx[4] = (_Float16)hi[0]; hx[5] = (_Float16)hi[1];
        hx[6] = (_Float16)hi[2]; hx[7] = (_Float16)hi[3];
        *reinterpret_cast<f16x8*>(&tile[r * HSTR + c8 * 8]) = hx;
    }
    __syncthreads();

    // ---- compute: wave wv handles M-subtile wv (16 rows) ----
    {
        const int m0 = wv * 16;
        f32x4 acc0 = { b1v, b1v, b1v, b1v };      // A-cols + b1
        f32x4 acc1 = { 0.f, 0.f, 0.f, 0.f };      // B-cols
#pragma unroll
        for (int ks = 0; ks < 4; ++ks) {
            // A-frag: row m0+n, k = 32*ks + 8*quad .. +7  (one ds_read_b128)
            f16x8 af = *reinterpret_cast<const f16x8*>(
                &tile[(m0 + n) * HSTR + 32 * ks + 8 * quad]);
            acc0 = __builtin_amdgcn_mfma_f32_16x16x32_f16(af, bfr[0][ks], acc0, 0, 0, 0);
            acc1 = __builtin_amdgcn_mfma_f32_16x16x32_f16(af, bfr[1][ks], acc1, 0, 0, 0);
        }
        // epilogue: D col = n, rows = m0 + quad*4 + reg. NT stores: A/B must
        // never sit dirty in this XCD's L2 (K2 gathers from all XCDs).
#pragma unroll
        for (int reg = 0; reg < 4; ++reg) {
            int node = base + m0 + quad * 4 + reg;
            if (node < N) {
                __builtin_nontemporal_store(
                    (_Float16)acc0[reg], reinterpret_cast<_Float16*>(A + node) + n);
                __builtin_nontemporal_store(
                    (_Float16)acc1[reg], reinterpret_cast<_Float16*>(B + node) + n);
            }
        }
    }

    // ---- TAIL: degree atomics (grid-stride; nt loads on the edge stream) ----
    {
        const int gtid = blockIdx.x * 256 + t;
        const int GT   = gridDim.x * 256;
        const int E4   = E >> 2;
        for (int q = gtid; q < E4; q += GT) {
            int e = q << 2;
            ix4 ii = __builtin_nontemporal_load(
                reinterpret_cast<const ix4*>(ind_i + e));
            fx4 vv = __builtin_nontemporal_load(
                reinterpret_cast<const fx4*>(val + e));
            atomicAdd(&deg[ii[0]], fabsf(vv[0]));
            atomicAdd(&deg[ii[1]], fabsf(vv[1]));
            atomicAdd(&deg[ii[2]], fabsf(vv[2]));
            atomicAdd(&deg[ii[3]], fabsf(vv[3]));
        }
        if (gtid < (E & 3)) {
            int e = (E & ~3) + gtid;
            atomicAdd(&deg[ind_i[e]], fabsf(val[e]));
        }
    }
}

// ============================================================================
// Shared MLP tail: x[17] -> L2 layer -> collapse -> exp. NO references/structs
// in the hot path (R1 lesson: addressable gather results -> alloca -> 672 MB
// scratch traffic). All indices compile-time; SROA keeps everything in VGPRs.
// ============================================================================
#define MLP_TAIL(X, EXOUT)                                                  \
    {                                                                       \
        float acc[L2DIM];                                                   \
        _Pragma("unroll")                                                   \
        for (int r = 0; r < L2DIM; ++r) acc[r] = b2s[r];                    \
        _Pragma("unroll")                                                   \
        for (int c = 0; c < L2DIM; ++c) {                                   \
            float xc = X[c];                                                \
            const float4* r4 = reinterpret_cast<const float4*>(&w2s[c * 20]); \
            float4 w0 = r4[0], w1v = r4[1], w2v = r4[2], w3 = r4[3];        \
            float  w16 = w2s[c * 20 + 16];                                  \
            acc[0]  += xc * w0.x;  acc[1]  += xc * w0.y;                    \
            acc[2]  += xc * w0.z;  acc[3]  += xc * w0.w;                    \
            acc[4]  += xc * w1v.x; acc[5]  += xc * w1v.y;                   \
            acc[6]  += xc * w1v.z; acc[7]  += xc * w1v.w;                   \
            acc[8]  += xc * w2v.x; acc[9]  += xc * w2v.y;                   \
            acc[10] += xc * w2v.z; acc[11] += xc * w2v.w;                   \
            acc[12] += xc * w3.x;  acc[13] += xc * w3.y;                    \
            acc[14] += xc * w3.z;  acc[15] += xc * w3.w;                    \
            acc[16] += xc * w16;                                            \
        }                                                                   \
        float ev = bc0s;                                                    \
        _Pragma("unroll")                                                   \
        for (int r = 0; r < L2DIM; ++r) ev += lrelu(acc[r]) * wcs[r];       \
        EXOUT = __expf(ev);                                                 \
    }

#define EDGE_X(X, ALO, AHI, BLO, BHI, V, D)                                 \
    _Pragma("unroll")                                                       \
    for (int k = 0; k < 8; ++k) {                                           \
        X[k]     = lrelu((float)ALO[k] + (float)BLO[k]);                    \
        X[k + 8] = lrelu((float)AHI[k] + (float)BHI[k]);                    \
    }                                                                       \
    X[L1OUT] = fabsf(V) / D;

// ============================================================================
// K2: per-edge MLP -> exp -> segment-sum. R2-exact structure (best: 58.2us):
// 256 threads, 2 edges/thread (e, e+E/2), lb(256,4). R11 adds: nt loads for
// ind/val (read-once streams out of L2), nt store for eout (write-once) --
// maximizing L2 residency for the A/B gather working set (6.4MB vs 4MB/XCD).
// A/B gather loads deliberately CACHED.
// Geometry exhausted (R0/R2/R5/R6/R8: 58-63); R8 refuted dispatch-rate; R7:
// lb(256,8) spills; R5/R6: ILP pins dead.
// ============================================================================
__global__ __launch_bounds__(256, 4) void edge_mlp(
    const int* __restrict__ ind, const float* __restrict__ val,
    const H16* __restrict__ A, const H16* __restrict__ B,
    const float* __restrict__ deg,
    const float* __restrict__ W2, const float* __restrict__ b2,
    const float* __restrict__ Wc, const float* __restrict__ bc,
    float* __restrict__ eout, float* __restrict__ ssum, int E)
{
    __shared__ float w2s[L2DIM * 20];   // row c at w2s[c*20], 16B-aligned
    __shared__ float b2s[L2DIM];
    __shared__ float wcs[L2DIM];
    __shared__ float bc0s;

    const int t = threadIdx.x;
    for (int idx = t; idx < L2DIM * L2DIM; idx += 256) {
        int c = idx / L2DIM, r = idx - c * L2DIM;
        w2s[c * 20 + r] = W2[idx];
    }
    if (t < L2DIM) b2s[t] = b2[t];
    if (t < L2DIM) wcs[t] = Wc[t];
    if (t == 0)    bc0s   = bc[0];
    __syncthreads();

    const int E2 = (E + 1) >> 1;          // pair stride
    const int p  = blockIdx.x * 256 + t;
    if (p >= E2) return;

    const int  e0   = p;
    const int  e1   = p + E2;
    const bool has1 = (e1 < E);
    const int  e1s  = has1 ? e1 : e0;     // safe clone address for tail

    // ---- issue the full load pipeline for both edges up front ----
    int i0 = __builtin_nontemporal_load(ind + e0);
    int j0 = __builtin_nontemporal_load(ind + E + e0);
    int i1 = __builtin_nontemporal_load(ind + e1s);
    int j1 = __builtin_nontemporal_load(ind + E + e1s);

    const f16x8* pA0 = reinterpret_cast<const f16x8*>(A + i0);
    const f16x8* pB0 = reinterpret_cast<const f16x8*>(B + j0);
    const f16x8* pA1 = reinterpret_cast<const f16x8*>(A + i1);
    const f16x8* pB1 = reinterpret_cast<const f16x8*>(B + j1);

    f16x8 a0lo = pA0[0], a0hi = pA0[1];   // cached gathers (working set)
    f16x8 b0lo = pB0[0], b0hi = pB0[1];
    float v0   = __builtin_nontemporal_load(val + e0);
    float d0   = deg[i0];
    f16x8 a1lo = pA1[0], a1hi = pA1[1];
    f16x8 b1lo = pB1[0], b1hi = pB1[1];
    float v1   = __builtin_nontemporal_load(val + e1s);
    float d1   = deg[i1];

    // ---- edge 0 ----
    {
        float x[L2DIM];
        EDGE_X(x, a0lo, a0hi, b0lo, b0hi, v0, d0);
        float ex0;
        MLP_TAIL(x, ex0);
        __builtin_nontemporal_store(ex0, eout + e0);
        atomicAdd(&ssum[i0], ex0);
    }

    // ---- edge 1 ----
    if (has1) {
        float x[L2DIM];
        EDGE_X(x, a1lo, a1hi, b1lo, b1hi, v1, d1);
        float ex1;
        MLP_TAIL(x, ex1);
        __builtin_nontemporal_store(ex1, eout + e1);
        atomicAdd(&ssum[i1], ex1);
    }
}

// ============================================================================
// K3: out = ex / s[i], 4 edges/thread vectorized. nt on the streams;
// ssum gathers cached (400KB, heavily reused).
// ============================================================================
__global__ void normalize(const int* __restrict__ ind_i, const float* __restrict__ ssum,
                          float* __restrict__ ex, int E) {
    int t = blockIdx.x * blockDim.x + threadIdx.x;
    int e = t * 4;
    if (e + 3 < E) {
        ix4 ii = __builtin_nontemporal_load(reinterpret_cast<const ix4*>(ind_i + e));
        fx4 vv = __builtin_nontemporal_load(reinterpret_cast<const fx4*>(ex + e));
        vv[0] /= ssum[ii[0]];
        vv[1] /= ssum[ii[1]];
        vv[2] /= ssum[ii[2]];
        vv[3] /= ssum[ii[3]];
        __builtin_nontemporal_store(vv, reinterpret_cast<fx4*>(ex + e));
    } else {
        for (; e < E; ++e) ex[e] = ex[e] / ssum[ind_i[e]];
    }
}

extern "C" void kernel_launch(void* const* d_in, const int* in_sizes, int n_in,
                              void* d_out, int out_size, void* d_ws, size_t ws_size,
                              hipStream_t stream) {
    const int*   Jt_ind = (const int*)  d_in[0];   // [2,E]
    const float* Jt_val = (const float*)d_in[1];   // [E]
    const float* f      = (const float*)d_in[2];   // [N,128]
    const float* W1 = (const float*)d_in[4];       // [256,16]
    const float* b1 = (const float*)d_in[5];       // [16]
    const float* W2 = (const float*)d_in[6];       // [17,17]
    const float* b2 = (const float*)d_in[7];       // [17]
    const float* Wc = (const float*)d_in[8];       // [17,1]
    const float* bc = (const float*)d_in[9];       // [1]

    const int E = in_sizes[1];
    const int N = in_sizes[2] / FDIM;
    float* out = (float*)d_out;                    // [E] fp32

    // workspace: deg[N] | ssum[N] (contiguous -> one memset) | A[N] | B[N]
    char* ws = (char*)d_ws;
    float* deg  = (float*)ws;  ws += (size_t)N * sizeof(float);
    float* ssum = (float*)ws;  ws += (size_t)N * sizeof(float);
    H16*   A    = (H16*)ws;    ws += (size_t)N * sizeof(H16);
    H16*   Bm   = (H16*)ws;    ws += (size_t)N * sizeof(H16);

    const int B256 = 256;
    const int nblk = (N + TRM - 1) / TRM;                   // 1563 node tiles
    const int E2   = (E + 1) / 2;                           // edge pairs
    const int eblk = (E2 + B256 - 1) / B256;                // 1563 blocks (R2)
    const int qblk = ((E + 3) / 4 + B256 - 1) / B256;       // 782 blocks

    hipMemsetAsync(deg, 0, 2 * (size_t)N * sizeof(float), stream);
    node_transform<<<nblk, B256, 0, stream>>>(f, W1, b1, Jt_ind, Jt_val,
                                              A, Bm, deg, N, E);
    edge_mlp      <<<eblk, B256, 0, stream>>>(Jt_ind, Jt_val, A, Bm, deg,
                                              W2, b2, Wc, bc, out, ssum, E);
    normalize     <<<qblk, B256, 0, stream>>>(Jt_ind, ssum, out, E);
}

// Round 12
// 211.323 us; speedup vs baseline: 1.0426x; 1.0426x over previous
//
#include <hip/hip_runtime.h>
#include <hip/hip_fp16.h>
#include <math.h>

#define FDIM  128
#define L1OUT 16
#define L2DIM 17
#define TRM   64      // f-rows per block (R6-proven geometry)
#define HSTR  136     // LDS tile row stride in halves (272 B: 2-way-only conflicts)

typedef _Float16 f16x8 __attribute__((ext_vector_type(8)));   // MFMA A/B frag (4 VGPR)
typedef float    f32x4 __attribute__((ext_vector_type(4)));   // MFMA C/D frag

// one 32-byte fp16 node row (16 halves); align 16 -> 2x global_load_dwordx4
struct __align__(16) H16 { __half2 h[8]; };

__device__ __forceinline__ float lrelu(float v) { return v >= 0.f ? v : 0.1f * v; }

// ============================================================================
// K1 (MFMA, pure): [A|B] = f @ W'. R12 structure:
//  - NO atomics here (R9 measured: atomics co-resident with K1's loads cost
//    ~20us; split K0+K1 ran ~35-43 combined vs 56-60 fused).
//  - Zeroes deg+ssum at its head (replaces the hipMemsetAsync dispatch; safe
//    because no atomic touches them until the NEXT kernel in the stream).
//  - R9's K2 regression (58->81) re-attributed: K1's 51MB f-stream evicted
//    ind/val/deg from L2 right before K2. Fix is ORDERING (degree_pass runs
//    between K1 and K2, re-warming those streams), not fusion.
// R11 lesson: nt hints neutral-to-negative everywhere; reverted.
// R4 lesson (permanent): cooperative grid.sync fusion -> 176us. Deleted.
// Layouts (HW-verified per guide): A-frag A[m=lane&15][k=(lane>>4)*8+j];
// B-frag B[k=(lane>>4)*8+j][n=lane&15]; C/D col=lane&15, row=(lane>>4)*4+reg.
// ============================================================================
__global__ void node_transform(
    const float* __restrict__ f, const float* __restrict__ W1,
    const float* __restrict__ b1,
    H16* __restrict__ A, H16* __restrict__ B,
    float* __restrict__ zeroz,        // deg|ssum contiguous, 2N floats
    int N)
{
    __shared__ __align__(16) _Float16 tile[TRM * HSTR];   // 17.4 KB

    const int t = threadIdx.x;

    // ---- zero deg+ssum (fire-and-forget coalesced stores; next kernel in
    // the stream is the first consumer) ----
    {
        const int gtid = blockIdx.x * 256 + t;
        const int Z4   = (2 * N) >> 2;
        if (gtid < Z4) {
            reinterpret_cast<float4*>(zeroz)[gtid] = make_float4(0.f, 0.f, 0.f, 0.f);
        }
        if (gtid < (2 * N & 3)) zeroz[(2 * N & ~3) + gtid] = 0.f;
    }

    const int lane = t & 63;
    const int wv   = t >> 6;          // wave 0..3 -> M-subtile wv
    const int n    = lane & 15;       // MFMA matrix-dim index (col)
    const int quad = lane >> 4;       // k-block / row-group selector

    // ---- load W' B-frags once per block: bfr[nt][ks], k = 32*ks + 8*quad + j
    f16x8 bfr[2][4];
#pragma unroll
    for (int nt = 0; nt < 2; ++nt)
#pragma unroll
        for (int ks = 0; ks < 4; ++ks) {
            f16x8 bf;
#pragma unroll
            for (int j = 0; j < 8; ++j) {
                int k = 32 * ks + 8 * quad + j;
                bf[j] = (_Float16)W1[(size_t)(nt * FDIM + k) * L1OUT + n];
            }
            bfr[nt][ks] = bf;
        }
    float b1v = b1[n];                // folded into nt=0 accumulator init

    // ---- stage 64 f-rows as fp16 into padded LDS tile (coalesced) ----
    const int base = blockIdx.x * TRM;
#pragma unroll
    for (int q = 0; q < 4; ++q) {
        int p  = t + 256 * q;         // half8-chunk index 0..1023
        int r  = p >> 4;              // 16 chunks per row
        int c8 = p & 15;              // chunk within row (8 halves)
        float4 lo = make_float4(0.f, 0.f, 0.f, 0.f);
        float4 hi = lo;
        if (base + r < N) {
            const float4* src = reinterpret_cast<const float4*>(
                f + (size_t)(base + r) * FDIM + c8 * 8);
            lo = src[0];
            hi = src[1];
        }
        f16x8 hx;
        hx[0] = (_Float16)lo.x; hx[1] = (_Float16)lo.y;
        hx[2] = (_Float16)lo.z; hx[3] = (_Float16)lo.w;
        hx[4] = (_Float16)hi.x; hx[5] = (_Float16)hi.y;
        hx[6] = (_Float16)hi.z; hx[7] = (_Float16)hi.w;
        *reinterpret_cast<f16x8*>(&tile[r * HSTR + c8 * 8]) = hx;
    }
    __syncthreads();

    // ---- compute: wave wv handles M-subtile wv (16 rows) ----
    {
        const int m0 = wv * 16;
        f32x4 acc0 = { b1v, b1v, b1v, b1v };      // A-cols + b1
        f32x4 acc1 = { 0.f, 0.f, 0.f, 0.f };      // B-cols
#pragma unroll
        for (int ks = 0; ks < 4; ++ks) {
            // A-frag: row m0+n, k = 32*ks + 8*quad .. +7  (one ds_read_b128)
            f16x8 af = *reinterpret_cast<const f16x8*>(
                &tile[(m0 + n) * HSTR + 32 * ks + 8 * quad]);
            acc0 = __builtin_amdgcn_mfma_f32_16x16x32_f16(af, bfr[0][ks], acc0, 0, 0, 0);
            acc1 = __builtin_amdgcn_mfma_f32_16x16x32_f16(af, bfr[1][ks], acc1, 0, 0, 0);
        }
        // epilogue: D col = n, rows = m0 + quad*4 + reg
#pragma unroll
        for (int reg = 0; reg < 4; ++reg) {
            int node = base + m0 + quad * 4 + reg;
            if (node < N) {
                reinterpret_cast<_Float16*>(A + node)[n] = (_Float16)acc0[reg];
                reinterpret_cast<_Float16*>(B + node)[n] = (_Float16)acc1[reg];
            }
        }
    }
}

// ============================================================================
// K0 (runs between K1 and K2): degree atomics only. Placement is deliberate:
// it re-reads ind/val (9.6MB) and writes deg immediately before edge_mlp,
// leaving exactly K2's front-end streams warm in L2 (the R10-fast cache
// state), while keeping the atomics out of K1's load window (the R9-proven
// ~15-20us interference win).
// ============================================================================
__global__ __launch_bounds__(256) void degree_pass(
    const int* __restrict__ ind_i, const float* __restrict__ val,
    float* __restrict__ deg, int E)
{
    const int gtid = blockIdx.x * 256 + threadIdx.x;
    const int GT   = gridDim.x * 256;
    const int E4   = E >> 2;
    for (int q = gtid; q < E4; q += GT) {
        int e = q << 2;
        int4   ii = *reinterpret_cast<const int4*>(ind_i + e);
        float4 vv = *reinterpret_cast<const float4*>(val + e);
        atomicAdd(&deg[ii.x], fabsf(vv.x));
        atomicAdd(&deg[ii.y], fabsf(vv.y));
        atomicAdd(&deg[ii.z], fabsf(vv.z));
        atomicAdd(&deg[ii.w], fabsf(vv.w));
    }
    if (gtid < (E & 3)) {
        int e = (E & ~3) + gtid;
        atomicAdd(&deg[ind_i[e]], fabsf(val[e]));
    }
}

// ============================================================================
// Shared MLP tail: x[17] -> L2 layer -> collapse -> exp. NO references/structs
// in the hot path (R1 lesson: addressable gather results -> alloca -> 672 MB
// scratch traffic). All indices compile-time; SROA keeps everything in VGPRs.
// ============================================================================
#define MLP_TAIL(X, EXOUT)                                                  \
    {                                                                       \
        float acc[L2DIM];                                                   \
        _Pragma("unroll")                                                   \
        for (int r = 0; r < L2DIM; ++r) acc[r] = b2s[r];                    \
        _Pragma("unroll")                                                   \
        for (int c = 0; c < L2DIM; ++c) {                                   \
            float xc = X[c];                                                \
            const float4* r4 = reinterpret_cast<const float4*>(&w2s[c * 20]); \
            float4 w0 = r4[0], w1v = r4[1], w2v = r4[2], w3 = r4[3];        \
            float  w16 = w2s[c * 20 + 16];                                  \
            acc[0]  += xc * w0.x;  acc[1]  += xc * w0.y;                    \
            acc[2]  += xc * w0.z;  acc[3]  += xc * w0.w;                    \
            acc[4]  += xc * w1v.x; acc[5]  += xc * w1v.y;                   \
            acc[6]  += xc * w1v.z; acc[7]  += xc * w1v.w;                   \
            acc[8]  += xc * w2v.x; acc[9]  += xc * w2v.y;                   \
            acc[10] += xc * w2v.z; acc[11] += xc * w2v.w;                   \
            acc[12] += xc * w3.x;  acc[13] += xc * w3.y;                    \
            acc[14] += xc * w3.z;  acc[15] += xc * w3.w;                    \
            acc[16] += xc * w16;                                            \
        }                                                                   \
        float ev = bc0s;                                                    \
        _Pragma("unroll")                                                   \
        for (int r = 0; r < L2DIM; ++r) ev += lrelu(acc[r]) * wcs[r];       \
        EXOUT = __expf(ev);                                                 \
    }

#define EDGE_X(X, ALO, AHI, BLO, BHI, V, D)                                 \
    _Pragma("unroll")                                                       \
    for (int k = 0; k < 8; ++k) {                                           \
        X[k]     = lrelu((float)ALO[k] + (float)BLO[k]);                    \
        X[k + 8] = lrelu((float)AHI[k] + (float)BHI[k]);                    \
    }                                                                       \
    X[L1OUT] = fabsf(V) / D;

// ============================================================================
// K2: per-edge MLP -> exp -> segment-sum. R10-exact (best measured: 58.4us in
// the 207.1 total): 256 threads, 2 edges/thread (e, e+E/2), lb(256,4), no nt.
// Geometry exhausted (R0/R2/R5/R6/R8: 58-63); R8 refuted dispatch-rate; R7:
// lb(256,8) spills; R5/R6: ILP pins dead; R11: nt hints hurt.
// ============================================================================
__global__ __launch_bounds__(256, 4) void edge_mlp(
    const int* __restrict__ ind, const float* __restrict__ val,
    const H16* __restrict__ A, const H16* __restrict__ B,
    const float* __restrict__ deg,
    const float* __restrict__ W2, const float* __restrict__ b2,
    const float* __restrict__ Wc, const float* __restrict__ bc,
    float* __restrict__ eout, float* __restrict__ ssum, int E)
{
    __shared__ float w2s[L2DIM * 20];   // row c at w2s[c*20], 16B-aligned
    __shared__ float b2s[L2DIM];
    __shared__ float wcs[L2DIM];
    __shared__ float bc0s;

    const int t = threadIdx.x;
    for (int idx = t; idx < L2DIM * L2DIM; idx += 256) {
        int c = idx / L2DIM, r = idx - c * L2DIM;
        w2s[c * 20 + r] = W2[idx];
    }
    if (t < L2DIM) b2s[t] = b2[t];
    if (t < L2DIM) wcs[t] = Wc[t];
    if (t == 0)    bc0s   = bc[0];
    __syncthreads();

    const int E2 = (E + 1) >> 1;          // pair stride
    const int p  = blockIdx.x * 256 + t;
    if (p >= E2) return;

    const int  e0   = p;
    const int  e1   = p + E2;
    const bool has1 = (e1 < E);
    const int  e1s  = has1 ? e1 : e0;     // safe clone address for tail

    // ---- issue the full load pipeline for both edges up front ----
    int i0 = ind[e0];   int j0 = ind[E + e0];
    int i1 = ind[e1s];  int j1 = ind[E + e1s];

    const f16x8* pA0 = reinterpret_cast<const f16x8*>(A + i0);
    const f16x8* pB0 = reinterpret_cast<const f16x8*>(B + j0);
    const f16x8* pA1 = reinterpret_cast<const f16x8*>(A + i1);
    const f16x8* pB1 = reinterpret_cast<const f16x8*>(B + j1);

    f16x8 a0lo = pA0[0], a0hi = pA0[1];   // 2x global_load_dwordx4 each
    f16x8 b0lo = pB0[0], b0hi = pB0[1];
    float v0   = val[e0];
    float d0   = deg[i0];
    f16x8 a1lo = pA1[0], a1hi = pA1[1];
    f16x8 b1lo = pB1[0], b1hi = pB1[1];
    float v1   = val[e1s];
    float d1   = deg[i1];

    // ---- edge 0 ----
    {
        float x[L2DIM];
        EDGE_X(x, a0lo, a0hi, b0lo, b0hi, v0, d0);
        float ex0;
        MLP_TAIL(x, ex0);
        eout[e0] = ex0;
        atomicAdd(&ssum[i0], ex0);
    }

    // ---- edge 1 ----
    if (has1) {
        float x[L2DIM];
        EDGE_X(x, a1lo, a1hi, b1lo, b1hi, v1, d1);
        float ex1;
        MLP_TAIL(x, ex1);
        eout[e1] = ex1;
        atomicAdd(&ssum[i1], ex1);
    }
}

// ============================================================================
// K3: out = ex / s[i], 4 edges/thread vectorized (R2-proven, no nt)
// ============================================================================
__global__ void normalize(const int* __restrict__ ind_i, const float* __restrict__ ssum,
                          float* __restrict__ ex, int E) {
    int t = blockIdx.x * blockDim.x + threadIdx.x;
    int e = t * 4;
    if (e + 3 < E) {
        int4   ii = *reinterpret_cast<const int4*>(ind_i + e);
        float4 vv = *reinterpret_cast<const float4*>(ex + e);
        vv.x /= ssum[ii.x];
        vv.y /= ssum[ii.y];
        vv.z /= ssum[ii.z];
        vv.w /= ssum[ii.w];
        *reinterpret_cast<float4*>(ex + e) = vv;
    } else {
        for (; e < E; ++e) ex[e] = ex[e] / ssum[ind_i[e]];
    }
}

extern "C" void kernel_launch(void* const* d_in, const int* in_sizes, int n_in,
                              void* d_out, int out_size, void* d_ws, size_t ws_size,
                              hipStream_t stream) {
    const int*   Jt_ind = (const int*)  d_in[0];   // [2,E]
    const float* Jt_val = (const float*)d_in[1];   // [E]
    const float* f      = (const float*)d_in[2];   // [N,128]
    const float* W1 = (const float*)d_in[4];       // [256,16]
    const float* b1 = (const float*)d_in[5];       // [16]
    const float* W2 = (const float*)d_in[6];       // [17,17]
    const float* b2 = (const float*)d_in[7];       // [17]
    const float* Wc = (const float*)d_in[8];       // [17,1]
    const float* bc = (const float*)d_in[9];       // [1]

    const int E = in_sizes[1];
    const int N = in_sizes[2] / FDIM;
    float* out = (float*)d_out;                    // [E] fp32

    // workspace: deg[N] | ssum[N] (contiguous -> zeroed by K1) | A[N] | B[N]
    char* ws = (char*)d_ws;
    float* deg  = (float*)ws;  ws += (size_t)N * sizeof(float);
    float* ssum = (float*)ws;  ws += (size_t)N * sizeof(float);
    H16*   A    = (H16*)ws;    ws += (size_t)N * sizeof(H16);
    H16*   Bm   = (H16*)ws;    ws += (size_t)N * sizeof(H16);

    const int B256 = 256;
    const int nblk = (N + TRM - 1) / TRM;                   // 1563 node tiles
    const int dblk = ((E + 3) / 4 + B256 - 1) / B256;       // 782 (degree pass)
    const int E2   = (E + 1) / 2;                           // edge pairs
    const int eblk = (E2 + B256 - 1) / B256;                // 1563 blocks
    const int qblk = ((E + 3) / 4 + B256 - 1) / B256;       // 782 blocks

    // Order: K1 (zeroes deg|ssum, writes A/B) -> K0 (atomics; re-warms
    // ind/val/deg for K2) -> K2 -> K3. No memset dispatch.
    node_transform<<<nblk, B256, 0, stream>>>(f, W1, b1, A, Bm, deg, N);
    degree_pass   <<<dblk, B256, 0, stream>>>(Jt_ind, Jt_val, deg, E);
    edge_mlp      <<<eblk, B256, 0, stream>>>(Jt_ind, Jt_val, A, Bm, deg,
                                              W2, b2, Wc, bc, out, ssum, E);
    normalize     <<<qblk, B256, 0, stream>>>(Jt_ind, ssum, out, E);
}

// Round 13
// 207.426 us; speedup vs baseline: 1.0622x; 1.0188x over previous
//
#include <hip/hip_runtime.h>
#include <hip/hip_fp16.h>
#include <math.h>

#define FDIM  128
#define L1OUT 16
#define L2DIM 17
#define TRM   64      // f-rows per tile (R6-proven geometry)
#define HSTR  136     // LDS tile row stride in halves (272 B: 2-way-only conflicts)
#define PBLK  1024    // persistent grid: 4 blocks/CU, all co-resident

typedef _Float16 f16x8 __attribute__((ext_vector_type(8)));   // MFMA A/B frag (4 VGPR)
typedef float    f32x4 __attribute__((ext_vector_type(4)));   // MFMA C/D frag

// one 32-byte fp16 node row (16 halves); align 16 -> 2x global_load_dwordx4
struct __align__(16) H16 { __half2 h[8]; };

__device__ __forceinline__ float lrelu(float v) { return v >= 0.f ? v : 0.1f * v; }

// ============================================================================
// K1 (MFMA, PERSISTENT, phase-separated): [A|B] = f @ W' then degree atomics.
// R9/R10/R12 synthesis: the atomics<->loads interference win (~15-20us, R9-
// measured) is real but a dispatch boundary costs the same (~15-20us) -- so
// buy the separation INSIDE one kernel. 1024 co-resident blocks (4/CU,
// lb(256,4), 17.4KB LDS) loop grid-stride over tiles (phase A: all loads/
// MFMA/stores), THEN run their slice of degree atomics (phase B). Unlike
// R10's 1563 staggered blocks (early tails overlapped late heads), phase A
// of all blocks runs concurrently and atomics only start as transforms
// drain. Bonus (R12-proven ordering effect): phase B re-reads ind/val and
// writes deg LAST -> K2 starts with warm streams.
// R7 evidence also favors persistent: longer-lived blocks -> residency/BW up.
// R4 lesson (permanent): cooperative grid.sync fusion -> 176us. Deleted.
// R11 lesson: nt hints neutral-to-negative; not used.
// Layouts (HW-verified per guide): A-frag A[m=lane&15][k=(lane>>4)*8+j];
// B-frag B[k=(lane>>4)*8+j][n=lane&15]; C/D col=lane&15, row=(lane>>4)*4+reg.
// deg zeroed by hipMemsetAsync before this kernel (required: in-kernel
// atomics need all of deg zeroed before ANY block's phase B).
// ============================================================================
__global__ __launch_bounds__(256, 4) void node_transform(
    const float* __restrict__ f, const float* __restrict__ W1,
    const float* __restrict__ b1,
    const int* __restrict__ ind_i, const float* __restrict__ val,
    H16* __restrict__ A, H16* __restrict__ B,
    float* __restrict__ deg, int N, int E, int NTILE)
{
    __shared__ __align__(16) _Float16 tile[TRM * HSTR];   // 17.4 KB

    const int t    = threadIdx.x;
    const int lane = t & 63;
    const int wv   = t >> 6;          // wave 0..3 -> M-subtile wv
    const int n    = lane & 15;       // MFMA matrix-dim index (col)
    const int quad = lane >> 4;       // k-block / row-group selector

    // ---- load W' B-frags once per block: bfr[nt][ks], k = 32*ks + 8*quad + j
    f16x8 bfr[2][4];
#pragma unroll
    for (int nt = 0; nt < 2; ++nt)
#pragma unroll
        for (int ks = 0; ks < 4; ++ks) {
            f16x8 bf;
#pragma unroll
            for (int j = 0; j < 8; ++j) {
                int k = 32 * ks + 8 * quad + j;
                bf[j] = (_Float16)W1[(size_t)(nt * FDIM + k) * L1OUT + n];
            }
            bfr[nt][ks] = bf;
        }
    const float b1v = b1[n];          // folded into nt=0 accumulator init

    // ================= PHASE A: tile loop (all loads/MFMA/stores) ==========
    for (int tb = blockIdx.x; tb < NTILE; tb += gridDim.x) {
        __syncthreads();              // prev iter's LDS reads done before restage
        const int base = tb * TRM;

        // ---- stage 64 f-rows as fp16 into padded LDS tile (coalesced) ----
#pragma unroll
        for (int q = 0; q < 4; ++q) {
            int p  = t + 256 * q;     // half8-chunk index 0..1023
            int r  = p >> 4;          // 16 chunks per row
            int c8 = p & 15;          // chunk within row (8 halves)
            float4 lo = make_float4(0.f, 0.f, 0.f, 0.f);
            float4 hi = lo;
            if (base + r < N) {
                const float4* src = reinterpret_cast<const float4*>(
                    f + (size_t)(base + r) * FDIM + c8 * 8);
                lo = src[0];
                hi = src[1];
            }
            f16x8 hx;
            hx[0] = (_Float16)lo.x; hx[1] = (_Float16)lo.y;
            hx[2] = (_Float16)lo.z; hx[3] = (_Float16)lo.w;
            hx[4] = (_Float16)hi.x; hx[5] = (_Float16)hi.y;
            hx[6] = (_Float16)hi.z; hx[7] = (_Float16)hi.w;
            *reinterpret_cast<f16x8*>(&tile[r * HSTR + c8 * 8]) = hx;
        }
        __syncthreads();

        // ---- compute: wave wv handles M-subtile wv (16 rows) ----
        const int m0 = wv * 16;
        f32x4 acc0 = { b1v, b1v, b1v, b1v };      // A-cols + b1
        f32x4 acc1 = { 0.f, 0.f, 0.f, 0.f };      // B-cols
#pragma unroll
        for (int ks = 0; ks < 4; ++ks) {
            // A-frag: row m0+n, k = 32*ks + 8*quad .. +7  (one ds_read_b128)
            f16x8 af = *reinterpret_cast<const f16x8*>(
                &tile[(m0 + n) * HSTR + 32 * ks + 8 * quad]);
            acc0 = __builtin_amdgcn_mfma_f32_16x16x32_f16(af, bfr[0][ks], acc0, 0, 0, 0);
            acc1 = __builtin_amdgcn_mfma_f32_16x16x32_f16(af, bfr[1][ks], acc1, 0, 0, 0);
        }
        // epilogue: D col = n, rows = m0 + quad*4 + reg
#pragma unroll
        for (int reg = 0; reg < 4; ++reg) {
            int node = base + m0 + quad * 4 + reg;
            if (node < N) {
                reinterpret_cast<_Float16*>(A + node)[n] = (_Float16)acc0[reg];
                reinterpret_cast<_Float16*>(B + node)[n] = (_Float16)acc1[reg];
            }
        }
    }

    // ================= PHASE B: degree atomics (after ALL owned tiles) =====
    {
        const int gtid = blockIdx.x * 256 + t;
        const int GT   = gridDim.x * 256;
        const int E4   = E >> 2;
        for (int q = gtid; q < E4; q += GT) {
            int e = q << 2;
            int4   ii = *reinterpret_cast<const int4*>(ind_i + e);
            float4 vv = *reinterpret_cast<const float4*>(val + e);
            atomicAdd(&deg[ii.x], fabsf(vv.x));
            atomicAdd(&deg[ii.y], fabsf(vv.y));
            atomicAdd(&deg[ii.z], fabsf(vv.z));
            atomicAdd(&deg[ii.w], fabsf(vv.w));
        }
        if (gtid < (E & 3)) {
            int e = (E & ~3) + gtid;
            atomicAdd(&deg[ind_i[e]], fabsf(val[e]));
        }
    }
}

// ============================================================================
// Shared MLP tail: x[17] -> L2 layer -> collapse -> exp. NO references/structs
// in the hot path (R1 lesson: addressable gather results -> alloca -> 672 MB
// scratch traffic). All indices compile-time; SROA keeps everything in VGPRs.
// ============================================================================
#define MLP_TAIL(X, EXOUT)                                                  \
    {                                                                       \
        float acc[L2DIM];                                                   \
        _Pragma("unroll")                                                   \
        for (int r = 0; r < L2DIM; ++r) acc[r] = b2s[r];                    \
        _Pragma("unroll")                                                   \
        for (int c = 0; c < L2DIM; ++c) {                                   \
            float xc = X[c];                                                \
            const float4* r4 = reinterpret_cast<const float4*>(&w2s[c * 20]); \
            float4 w0 = r4[0], w1v = r4[1], w2v = r4[2], w3 = r4[3];        \
            float  w16 = w2s[c * 20 + 16];                                  \
            acc[0]  += xc * w0.x;  acc[1]  += xc * w0.y;                    \
            acc[2]  += xc * w0.z;  acc[3]  += xc * w0.w;                    \
            acc[4]  += xc * w1v.x; acc[5]  += xc * w1v.y;                   \
            acc[6]  += xc * w1v.z; acc[7]  += xc * w1v.w;                   \
            acc[8]  += xc * w2v.x; acc[9]  += xc * w2v.y;                   \
            acc[10] += xc * w2v.z; acc[11] += xc * w2v.w;                   \
            acc[12] += xc * w3.x;  acc[13] += xc * w3.y;                    \
            acc[14] += xc * w3.z;  acc[15] += xc * w3.w;                    \
            acc[16] += xc * w16;                                            \
        }                                                                   \
        float ev = bc0s;                                                    \
        _Pragma("unroll")                                                   \
        for (int r = 0; r < L2DIM; ++r) ev += lrelu(acc[r]) * wcs[r];       \
        EXOUT = __expf(ev);                                                 \
    }

#define EDGE_X(X, ALO, AHI, BLO, BHI, V, D)                                 \
    _Pragma("unroll")                                                       \
    for (int k = 0; k < 8; ++k) {                                           \
        X[k]     = lrelu((float)ALO[k] + (float)BLO[k]);                    \
        X[k + 8] = lrelu((float)AHI[k] + (float)BHI[k]);                    \
    }                                                                       \
    X[L1OUT] = fabsf(V) / D;

// ============================================================================
// K2: per-edge MLP -> exp -> segment-sum. R10-exact (best measured 58.4us in
// the 207.1 total): 256 threads, 2 edges/thread (e, e+E/2), lb(256,4), no nt.
// Geometry exhausted (R0/R2/R5/R6/R8: 58-63); R8 refuted dispatch-rate; R7:
// lb(256,8) spills; R5/R6: ILP pins dead; R11: nt hints hurt.
// ============================================================================
__global__ __launch_bounds__(256, 4) void edge_mlp(
    const int* __restrict__ ind, const float* __restrict__ val,
    const H16* __restrict__ A, const H16* __restrict__ B,
    const float* __restrict__ deg,
    const float* __restrict__ W2, const float* __restrict__ b2,
    const float* __restrict__ Wc, const float* __restrict__ bc,
    float* __restrict__ eout, float* __restrict__ ssum, int E)
{
    __shared__ float w2s[L2DIM * 20];   // row c at w2s[c*20], 16B-aligned
    __shared__ float b2s[L2DIM];
    __shared__ float wcs[L2DIM];
    __shared__ float bc0s;

    const int t = threadIdx.x;
    for (int idx = t; idx < L2DIM * L2DIM; idx += 256) {
        int c = idx / L2DIM, r = idx - c * L2DIM;
        w2s[c * 20 + r] = W2[idx];
    }
    if (t < L2DIM) b2s[t] = b2[t];
    if (t < L2DIM) wcs[t] = Wc[t];
    if (t == 0)    bc0s   = bc[0];
    __syncthreads();

    const int E2 = (E + 1) >> 1;          // pair stride
    const int p  = blockIdx.x * 256 + t;
    if (p >= E2) return;

    const int  e0   = p;
    const int  e1   = p + E2;
    const bool has1 = (e1 < E);
    const int  e1s  = has1 ? e1 : e0;     // safe clone address for tail

    // ---- issue the full load pipeline for both edges up front ----
    int i0 = ind[e0];   int j0 = ind[E + e0];
    int i1 = ind[e1s];  int j1 = ind[E + e1s];

    const f16x8* pA0 = reinterpret_cast<const f16x8*>(A + i0);
    const f16x8* pB0 = reinterpret_cast<const f16x8*>(B + j0);
    const f16x8* pA1 = reinterpret_cast<const f16x8*>(A + i1);
    const f16x8* pB1 = reinterpret_cast<const f16x8*>(B + j1);

    f16x8 a0lo = pA0[0], a0hi = pA0[1];   // 2x global_load_dwordx4 each
    f16x8 b0lo = pB0[0], b0hi = pB0[1];
    float v0   = val[e0];
    float d0   = deg[i0];
    f16x8 a1lo = pA1[0], a1hi = pA1[1];
    f16x8 b1lo = pB1[0], b1hi = pB1[1];
    float v1   = val[e1s];
    float d1   = deg[i1];

    // ---- edge 0 ----
    {
        float x[L2DIM];
        EDGE_X(x, a0lo, a0hi, b0lo, b0hi, v0, d0);
        float ex0;
        MLP_TAIL(x, ex0);
        eout[e0] = ex0;
        atomicAdd(&ssum[i0], ex0);
    }

    // ---- edge 1 ----
    if (has1) {
        float x[L2DIM];
        EDGE_X(x, a1lo, a1hi, b1lo, b1hi, v1, d1);
        float ex1;
        MLP_TAIL(x, ex1);
        eout[e1] = ex1;
        atomicAdd(&ssum[i1], ex1);
    }
}

// ============================================================================
// K3: out = ex / s[i], 4 edges/thread vectorized (R2-proven, no nt)
// ============================================================================
__global__ void normalize(const int* __restrict__ ind_i, const float* __restrict__ ssum,
                          float* __restrict__ ex, int E) {
    int t = blockIdx.x * blockDim.x + threadIdx.x;
    int e = t * 4;
    if (e + 3 < E) {
        int4   ii = *reinterpret_cast<const int4*>(ind_i + e);
        float4 vv = *reinterpret_cast<const float4*>(ex + e);
        vv.x /= ssum[ii.x];
        vv.y /= ssum[ii.y];
        vv.z /= ssum[ii.z];
        vv.w /= ssum[ii.w];
        *reinterpret_cast<float4*>(ex + e) = vv;
    } else {
        for (; e < E; ++e) ex[e] = ex[e] / ssum[ind_i[e]];
    }
}

extern "C" void kernel_launch(void* const* d_in, const int* in_sizes, int n_in,
                              void* d_out, int out_size, void* d_ws, size_t ws_size,
                              hipStream_t stream) {
    const int*   Jt_ind = (const int*)  d_in[0];   // [2,E]
    const float* Jt_val = (const float*)d_in[1];   // [E]
    const float* f      = (const float*)d_in[2];   // [N,128]
    const float* W1 = (const float*)d_in[4];       // [256,16]
    const float* b1 = (const float*)d_in[5];       // [16]
    const float* W2 = (const float*)d_in[6];       // [17,17]
    const float* b2 = (const float*)d_in[7];       // [17]
    const float* Wc = (const float*)d_in[8];       // [17,1]
    const float* bc = (const float*)d_in[9];       // [1]

    const int E = in_sizes[1];
    const int N = in_sizes[2] / FDIM;
    float* out = (float*)d_out;                    // [E] fp32

    // workspace: deg[N] | ssum[N] (contiguous -> one memset) | A[N] | B[N]
    char* ws = (char*)d_ws;
    float* deg  = (float*)ws;  ws += (size_t)N * sizeof(float);
    float* ssum = (float*)ws;  ws += (size_t)N * sizeof(float);
    H16*   A    = (H16*)ws;    ws += (size_t)N * sizeof(H16);
    H16*   Bm   = (H16*)ws;    ws += (size_t)N * sizeof(H16);

    const int B256  = 256;
    const int NTILE = (N + TRM - 1) / TRM;                  // 1563 tiles
    const int pblk  = NTILE < PBLK ? NTILE : PBLK;          // persistent grid
    const int E2    = (E + 1) / 2;                          // edge pairs
    const int eblk  = (E2 + B256 - 1) / B256;               // 1563 blocks
    const int qblk  = ((E + 3) / 4 + B256 - 1) / B256;      // 782 blocks

    hipMemsetAsync(deg, 0, 2 * (size_t)N * sizeof(float), stream);
    node_transform<<<pblk, B256, 0, stream>>>(f, W1, b1, Jt_ind, Jt_val,
                                              A, Bm, deg, N, E, NTILE);
    edge_mlp      <<<eblk, B256, 0, stream>>>(Jt_ind, Jt_val, A, Bm, deg,
                                              W2, b2, Wc, bc, out, ssum, E);
    normalize     <<<qblk, B256, 0, stream>>>(Jt_ind, ssum, out, E);
}